// Round 2
// baseline (594.060 us; speedup 1.0000x reference)
//
#include <hip/hip_runtime.h>
#include <hip/hip_bf16.h>

#define Bb 256
#define Ll 200
#define Dd 128
#define BL (Bb*Ll)

typedef __hip_bfloat16 bf16;
typedef __attribute__((ext_vector_type(8))) short short8;
typedef __attribute__((ext_vector_type(4))) float floatx4;

__device__ __forceinline__ float b2f(bf16 v) { return __bfloat162float(v); }
__device__ __forceinline__ bf16  f2b(float v) { return __float2bfloat16(v); }
// dtype-agnostic load: f32 flag selects float32 vs bf16 interpretation
__device__ __forceinline__ float ldf(const void* p, int i, int f32) {
  return f32 ? ((const float*)p)[i] : b2f(((const bf16*)p)[i]);
}

// ---------------------------------------------------------------- K-1: dtype detect (1 wave)
// bf16 weights are uniform(-0.088,0.088): exponent field <= 0x7E for every uint16.
// f32 data read as uint16 pairs: even lanes are raw mantissa bits -> exp>=0x7F ~50% each.
__global__ void k_detect(const unsigned short* __restrict__ w, int* __restrict__ flag) {
  int lane = threadIdx.x;
  unsigned short u = w[lane];
  int e = (u >> 7) & 0xFF;
  unsigned long long bad = __ballot(e >= 0x7F);
  if (lane == 0) *flag = (bad != 0ull) ? 1 : 0;   // 1 = float32, 0 = bf16
}

// ---------------------------------------------------------------- K0: canonicalize weights/biases
struct PackP {
  const void *W_ei,*W_eo,*w_ih,*w_hh,*Wk,*Wv,*Wqp,*Wop,*W1p,*W2p,*pos;
  const void *b_ei,*b_eo,*b_ih,*b_hh,*bk,*bv,*bqp,*bop,*b1p,*b2p,*biah,*boah;
  const void *ln1g,*ln1b,*ln2g,*ln2b,*lnfg,*lnfb;
  const int* flag;
  bf16 *cWhe,*cWih,*cWhh,*cWkv,*cWq,*cWo,*cW1,*cW2,*cPos;
  float *bias_he,*bias_gi,*bias_gh,*bias_kv,*cbq,*cbo,*cb1,*cb2,*cbiah,*cboah,*cln;
};
__global__ __launch_bounds__(256) void k0_pack(PackP p) {
  int idx = blockIdx.x * 256 + threadIdx.x;       // < 306944
  int f32 = *p.flag;
  if (idx < 131072) {
    if (idx < 32768) {
      int r = idx >> 7, c = idx & 127;
      p.cWhe[idx] = f2b(r < 128 ? ldf(p.W_ei, r*128+c, f32) : ldf(p.W_eo, (r-128)*128+c, f32));
    } else p.cWih[idx-32768] = f2b(ldf(p.w_ih, idx-32768, f32));
  } else if (idx < 278528) {
    if (idx < 180224)      p.cWhh[idx-131072] = f2b(ldf(p.w_hh, idx-131072, f32));
    else if (idx < 212992) {
      int i = idx - 180224; int r = i >> 7, c = i & 127;
      p.cWkv[i] = f2b(r < 128 ? ldf(p.Wk, r*128+c, f32) : ldf(p.Wv, (r-128)*128+c, f32));
    }
    else if (idx < 229376) p.cWq[idx-212992] = f2b(ldf(p.Wqp, idx-212992, f32));
    else if (idx < 245760) p.cWo[idx-229376] = f2b(ldf(p.Wop, idx-229376, f32));
    else if (idx < 262144) p.cW1[idx-245760] = f2b(ldf(p.W1p, idx-245760, f32));
    else                   p.cW2[idx-262144] = f2b(ldf(p.W2p, idx-262144, f32));
  } else if (idx < 304128) {
    p.cPos[idx-278528] = f2b(ldf(p.pos, idx-278528, f32));
  } else {
    int j = idx - 304128;                          // < 2816
    if      (j < 256)  p.bias_he[j]     = (j<128) ? ldf(p.b_ei,j,f32) : ldf(p.b_eo,j-128,f32);
    else if (j < 640)  p.bias_gi[j-256] = ldf(p.b_ih, j-256, f32);
    else if (j < 1024) p.bias_gh[j-640] = ldf(p.b_hh, j-640, f32);
    else if (j < 1280) { int c=j-1024; p.bias_kv[c] = (c<128)? ldf(p.bk,c,f32): ldf(p.bv,c-128,f32); }
    else if (j < 1408) p.cbq[j-1280]   = ldf(p.bqp, j-1280, f32);
    else if (j < 1536) p.cbo[j-1408]   = ldf(p.bop, j-1408, f32);
    else if (j < 1664) p.cb1[j-1536]   = ldf(p.b1p, j-1536, f32);
    else if (j < 1792) p.cb2[j-1664]   = ldf(p.b2p, j-1664, f32);
    else if (j < 1920) p.cbiah[j-1792] = ldf(p.biah, j-1792, f32);
    else if (j < 2048) p.cboah[j-1920] = ldf(p.boah, j-1920, f32);
    else {
      int i = j - 2048, g = i >> 7, c2 = i & 127;  // ln1_g,ln1_b,ln2_g,ln2_b,lnf_g,lnf_b
      const void* s6 = g==0?p.ln1g: g==1?p.ln1b: g==2?p.ln2g: g==3?p.ln2b: g==4?p.lnfg: p.lnfb;
      p.cln[i] = ldf(s6, c2, f32);
    }
  }
}

// ---------------------------------------------------------------- K1: graph build (one block per batch row)
__global__ __launch_bounds__(256) void k1_graph(const int* __restrict__ seqs,
    int* __restrict__ alias_g, int* __restrict__ items_g,
    float* __restrict__ rin_g, float* __restrict__ rout_g,
    unsigned* __restrict__ adj_g, unsigned* __restrict__ adjT_g)
{
  __shared__ int s[Ll], al[Ll], its[Ll];
  __shared__ unsigned char isf[Ll];
  __shared__ unsigned adjL[Ll*8], adjTL[Ll*8];
  int b = blockIdx.x, t = threadIdx.x;
  if (t < Ll) s[t] = seqs[b*Ll + t];
  for (int i = t; i < Ll*8; i += 256) { adjL[i] = 0u; adjTL[i] = 0u; }
  __syncthreads();
  if (t < Ll) {                      // first-occurrence flag (original order)
    int v = s[t]; bool f = true;
    for (int j = 0; j < t; j++) if (s[j] == v) { f = false; break; }
    isf[t] = f ? 1 : 0; its[t] = 0;
  }
  __syncthreads();
  if (t < Ll) {                      // alias = #distinct values < s[t]
    int v = s[t], r = 0;
    for (int j = 0; j < Ll; j++) r += (isf[j] && s[j] < v);
    al[t] = r;
  }
  __syncthreads();
  if (t < Ll && isf[t]) its[al[t]] = s[t];        // items[rank] = value
  if (t < Ll-1 && s[t+1] > 0) {                   // edges alias[t] -> alias[t+1]
    int u = al[t], v = al[t+1];
    atomicOr(&adjL [u*8 + (v >> 5)], 1u << (v & 31));
    atomicOr(&adjTL[v*8 + (u >> 5)], 1u << (u & 31));
  }
  __syncthreads();
  if (t < Ll) {
    int od = 0, id = 0;
    for (int wd = 0; wd < 7; wd++) { od += __popc(adjL[t*8+wd]); id += __popc(adjTL[t*8+wd]); }
    rout_g [b*Ll + t] = 1.0f / (float)max(od, 1);
    rin_g  [b*Ll + t] = 1.0f / (float)max(id, 1);
    alias_g[b*Ll + t] = al[t];
    items_g[b*Ll + t] = its[t];
  }
  for (int i = t; i < Ll*8; i += 256) { adj_g[b*Ll*8 + i] = adjL[i]; adjT_g[b*Ll*8 + i] = adjTL[i]; }
}

// ---------------------------------------------------------------- K2: gather item embeddings (dtype-agnostic)
__global__ __launch_bounds__(256) void k2_gather(const void* __restrict__ emb, const int* __restrict__ flag,
    const int* __restrict__ items_g, bf16* __restrict__ hidden)
{
  int idx = blockIdx.x * 256 + threadIdx.x;       // < BL*128
  int f32 = *flag;
  int n = idx >> 7, c = idx & 127;
  hidden[idx] = f2b(ldf(emb, items_g[n] * Dd + c, f32));
}

// ---------------------------------------------------------------- MFMA GEMM: out[m,n] = sum_k A[m,k]*W[n,k] + bias[n]
template<int K, int N>
__global__ __launch_bounds__(256) void gemm(const bf16* __restrict__ A, const bf16* __restrict__ W,
                                            const float* __restrict__ bias, bf16* __restrict__ out)
{
  int wave = threadIdx.x >> 6, lane = threadIdx.x & 63;
  int m0 = blockIdx.x * 64 + wave * 16;
  int q = lane >> 4, mr = lane & 15;
  const short* Ap = (const short*)A + (size_t)(m0 + mr) * K + q * 8;
  short8 afr[K/32];
#pragma unroll
  for (int kk = 0; kk < K/32; kk++) afr[kk] = *(const short8*)(Ap + kk*32);
  for (int nt = 0; nt < N/16; nt++) {
    int n = nt*16 + mr;
    const short* Wp = (const short*)W + (size_t)n * K + q * 8;
    floatx4 acc = {0.f, 0.f, 0.f, 0.f};
#pragma unroll
    for (int kk = 0; kk < K/32; kk++) {
      short8 bfr = *(const short8*)(Wp + kk*32);
      acc = __builtin_amdgcn_mfma_f32_16x16x32_bf16(afr[kk], bfr, acc, 0, 0, 0);
    }
    float bs = bias[n];
#pragma unroll
    for (int i = 0; i < 4; i++) {     // D: col=lane&15, row=quad*4+i
      int orow = m0 + q*4 + i;
      out[(size_t)orow * N + n] = f2b(acc[i] + bs);
    }
  }
}

// ---------------------------------------------------------------- K3: sparse graph aggregation
__global__ __launch_bounds__(256) void k3_agg(const bf16* __restrict__ he,
    const unsigned* __restrict__ adj_g, const unsigned* __restrict__ adjT_g,
    const float* __restrict__ rin_g, const float* __restrict__ rout_g,
    const float* __restrict__ cbiah, const float* __restrict__ cboah, bf16* __restrict__ hio)
{
  __shared__ unsigned m_in[Ll*8], m_out[Ll*8];
  __shared__ float r_in[Ll], r_out[Ll];
  int b = blockIdx.x, t = threadIdx.x;
  for (int i = t; i < Ll*8; i += 256) { m_out[i] = adj_g[b*Ll*8 + i]; m_in[i] = adjT_g[b*Ll*8 + i]; }
  if (t < Ll) { r_in[t] = rin_g[b*Ll + t]; r_out[t] = rout_g[b*Ll + t]; }
  int c = t;
  bool grp_in = (c < 128);
  float bias = grp_in ? cbiah[c] : cboah[c-128];
  __syncthreads();
  const bf16* heb = he + (size_t)b * Ll * 256;
  bf16* hiob = hio + (size_t)b * Ll * 256;
  for (int i = 0; i < Ll; i++) {
    const unsigned* mask = grp_in ? &m_in[i*8] : &m_out[i*8];
    float acc = 0.f;
    for (int wd = 0; wd < 7; wd++) {
      unsigned bits = mask[wd];
      while (bits) { int j = (wd << 5) + __builtin_ctz(bits); bits &= bits - 1;
        acc += b2f(heb[(size_t)j*256 + c]); }
    }
    float r = grp_in ? r_in[i] : r_out[i];
    hiob[(size_t)i*256 + c] = f2b(bias + r * acc);
  }
}

// ---------------------------------------------------------------- K4: GRU cell elementwise
__global__ __launch_bounds__(256) void k4_gru(const bf16* __restrict__ gi, const bf16* __restrict__ gh,
                                              bf16* __restrict__ hidden)
{
  int idx = blockIdx.x * 256 + threadIdx.x;       // < BL*128
  int n = idx >> 7, j = idx & 127;
  const bf16* gin = gi + (size_t)n * 384;
  const bf16* ghn = gh + (size_t)n * 384;
  float ir = b2f(gin[j]), ii = b2f(gin[128+j]), inn = b2f(gin[256+j]);
  float hr = b2f(ghn[j]), hi = b2f(ghn[128+j]), hn = b2f(ghn[256+j]);
  float r  = 1.f / (1.f + expf(-(ir + hr)));
  float z  = 1.f / (1.f + expf(-(ii + hi)));
  float ng = tanhf(inn + r * hn);
  float h  = b2f(hidden[idx]);
  hidden[idx] = f2b(ng + z * (h - ng));
}

// ---------------------------------------------------------------- K5: seq gather + pos emb + mask; save ht
__global__ __launch_bounds__(256) void k5_x(const bf16* __restrict__ hidden, const int* __restrict__ alias_g,
    const int* __restrict__ seqs, const int* __restrict__ lens,
    const bf16* __restrict__ cPos, bf16* __restrict__ x, float* __restrict__ ht)
{
  int idx = blockIdx.x * 256 + threadIdx.x;       // < BL*128
  int c = idx & 127; int bt = idx >> 7; int tpos = bt % Ll; int b = bt / Ll;
  int a = alias_g[bt];
  float sh = b2f(hidden[((size_t)b*Ll + a) * Dd + c]);
  float val = (seqs[bt] > 0) ? sh + b2f(cPos[tpos*Dd + c]) : 0.f;
  x[idx] = f2b(val);
  if (tpos == lens[b] - 1) ht[b*Dd + c] = sh;
}

// ---------------------------------------------------------------- K7: per-batch tail
struct FinalP {
  const bf16 *x, *kv; const float* ht;
  const bf16 *cWq, *cWo, *cW1, *cW2;
  const float *cbq, *cbo, *cb1, *cb2, *cln;       // cln: ln1_g,ln1_b,ln2_g,ln2_b,lnf_g,lnf_b (6x128)
  const int* lens; const int* flag;
  void* out;
};
__device__ float block_sum(float v, float* red) {
  int t = threadIdx.x;
  red[t] = v; __syncthreads();
  for (int s = 128; s > 0; s >>= 1) { if (t < s) red[t] += red[t+s]; __syncthreads(); }
  float r = red[0]; __syncthreads(); return r;
}
__device__ float block_max(float v, float* red) {
  int t = threadIdx.x;
  red[t] = v; __syncthreads();
  for (int s = 128; s > 0; s >>= 1) { if (t < s) red[t] = fmaxf(red[t], red[t+s]); __syncthreads(); }
  float r = red[0]; __syncthreads(); return r;
}
__global__ __launch_bounds__(256) void k7_final(FinalP p)
{
  __shared__ float red[256];
  __shared__ float pb[256];
  __shared__ float qin[128], qv[128], aout[128], hh[128], f1[128];
  int b = blockIdx.x, t = threadIdx.x, c = t;
  int li = p.lens[b] - 1;
  int f32 = *p.flag;
  // LN1 on x[b,li]
  float xv = (c < 128) ? b2f(p.x[((size_t)b*Ll + li) * Dd + c]) : 0.f;
  float mu = block_sum((c < 128) ? xv : 0.f, red) * (1.f/128.f);
  float d  = (c < 128) ? xv - mu : 0.f;
  float var = block_sum(d*d, red) * (1.f/128.f);
  float rs = rsqrtf(var + 1e-5f);
  if (c < 128) qin[c] = d * rs * p.cln[c] + p.cln[128+c];
  __syncthreads();
  // q = qin @ Wq^T + bq
  if (c < 128) {
    float acc = p.cbq[c];
    const bf16* wr = p.cWq + c*128;
    for (int k = 0; k < 128; k++) acc += qin[k] * b2f(wr[k]);
    qv[c] = acc;
  }
  __syncthreads();
  const bf16* kvb = p.kv + (size_t)b * Ll * 256;
  for (int h = 0; h < 2; h++) {
    float sc = -3.0e38f;
    if (t <= li) {
      const bf16* kr = kvb + (size_t)t*256 + h*64;
      float s_ = 0.f;
      for (int d2 = 0; d2 < 64; d2++) s_ += qv[h*64 + d2] * b2f(kr[d2]);
      sc = s_ * 0.125f;
    }
    float m = block_max(sc, red);
    float e = (t <= li) ? expf(sc - m) : 0.f;
    pb[t] = e;
    float l = block_sum(e, red);
    if (t < 64) {
      float acc = 0.f;
      for (int j = 0; j <= li; j++) acc += pb[j] * b2f(kvb[(size_t)j*256 + 128 + h*64 + t]);
      aout[h*64 + t] = acc / l;
    }
    __syncthreads();
  }
  // mo + residual
  float x2v = 0.f;
  if (c < 128) {
    float acc = p.cbo[c];
    const bf16* wr = p.cWo + c*128;
    for (int k = 0; k < 128; k++) acc += aout[k] * b2f(wr[k]);
    x2v = qin[c] + acc;
  }
  // LN2
  mu = block_sum((c < 128) ? x2v : 0.f, red) * (1.f/128.f);
  d  = (c < 128) ? x2v - mu : 0.f;
  var = block_sum(d*d, red) * (1.f/128.f);
  rs = rsqrtf(var + 1e-5f);
  if (c < 128) hh[c] = d * rs * p.cln[256+c] + p.cln[384+c];
  __syncthreads();
  // FFN
  if (c < 128) {
    float acc = p.cb1[c];
    const bf16* wr = p.cW1 + c*128;
    for (int k = 0; k < 128; k++) acc += hh[k] * b2f(wr[k]);
    f1[c] = fmaxf(acc, 0.f);
  }
  __syncthreads();
  float x3v = 0.f;
  if (c < 128) {
    float acc = p.cb2[c];
    const bf16* wr = p.cW2 + c*128;
    for (int k = 0; k < 128; k++) acc += f1[k] * b2f(wr[k]);
    x3v = hh[c] + acc;
  }
  // LNf + mix with ht
  mu = block_sum((c < 128) ? x3v : 0.f, red) * (1.f/128.f);
  d  = (c < 128) ? x3v - mu : 0.f;
  var = block_sum(d*d, red) * (1.f/128.f);
  rs = rsqrtf(var + 1e-5f);
  if (c < 128) {
    float lf = d * rs * p.cln[512+c] + p.cln[640+c];
    float outv = 0.6f * lf + 0.4f * p.ht[b*Dd + c];
    if (f32) ((float*)p.out)[b*Dd + c] = outv;
    else     ((bf16*)p.out)[b*Dd + c]  = f2b(outv);
  }
}

// ---------------------------------------------------------------- host
extern "C" void kernel_launch(void* const* d_in, const int* in_sizes, int n_in,
                              void* d_out, int out_size, void* d_ws, size_t ws_size,
                              hipStream_t stream)
{
  (void)in_sizes; (void)n_in; (void)out_size; (void)ws_size;
  const void* item_emb = d_in[0];
  const void* pos_emb  = d_in[1];
  const int* seqs = (const int*)d_in[30];
  const int* lens = (const int*)d_in[31];

  char* wsp = (char*)d_ws;
  size_t o = 0;
  auto alloc = [&](size_t sz) { void* p = wsp + o; o += (sz + 255) & ~(size_t)255; return p; };
  int*      flag    = (int*)alloc(4);
  int*      alias_g = (int*)alloc((size_t)BL*4);
  int*      items_g = (int*)alloc((size_t)BL*4);
  float*    rin_g   = (float*)alloc((size_t)BL*4);
  float*    rout_g  = (float*)alloc((size_t)BL*4);
  unsigned* adj_g   = (unsigned*)alloc((size_t)BL*8*4);
  unsigned* adjT_g  = (unsigned*)alloc((size_t)BL*8*4);
  float*    ht_g    = (float*)alloc((size_t)Bb*Dd*4);
  bf16*     cWhe    = (bf16*)alloc(32768*2);
  bf16*     cWih    = (bf16*)alloc(98304*2);
  bf16*     cWhh    = (bf16*)alloc(49152*2);
  bf16*     cWkv    = (bf16*)alloc(32768*2);
  bf16*     cWq     = (bf16*)alloc(16384*2);
  bf16*     cWo     = (bf16*)alloc(16384*2);
  bf16*     cW1     = (bf16*)alloc(16384*2);
  bf16*     cW2     = (bf16*)alloc(16384*2);
  bf16*     cPos    = (bf16*)alloc(25600*2);
  float*    bias_he = (float*)alloc(256*4);
  float*    bias_gi = (float*)alloc(384*4);
  float*    bias_gh = (float*)alloc(384*4);
  float*    bias_kv = (float*)alloc(256*4);
  float*    cbq     = (float*)alloc(128*4);
  float*    cbo     = (float*)alloc(128*4);
  float*    cb1     = (float*)alloc(128*4);
  float*    cb2     = (float*)alloc(128*4);
  float*    cbiah   = (float*)alloc(128*4);
  float*    cboah   = (float*)alloc(128*4);
  float*    cln     = (float*)alloc(768*4);
  bf16*     hidden  = (bf16*)alloc((size_t)BL*128*2);
  bf16*     he      = (bf16*)alloc((size_t)BL*256*2);
  bf16*     hio     = (bf16*)alloc((size_t)BL*256*2);
  bf16*     gi      = (bf16*)alloc((size_t)BL*384*2);
  bf16*     gh      = (bf16*)alloc((size_t)BL*384*2);
  bf16*     x  = he;    // reuse: he dead after k3_agg
  bf16*     kv = hio;   // reuse: hio dead after gi GEMM

  k_detect<<<1, 64, 0, stream>>>((const unsigned short*)d_in[2], flag);
  PackP pp = { d_in[2], d_in[4], d_in[8], d_in[10], d_in[16], d_in[18], d_in[14], d_in[20],
               d_in[24], d_in[26], d_in[1],
               d_in[3], d_in[5], d_in[9], d_in[11], d_in[17], d_in[19], d_in[15], d_in[21],
               d_in[25], d_in[27], d_in[6], d_in[7],
               d_in[12], d_in[13], d_in[22], d_in[23], d_in[28], d_in[29],
               flag,
               cWhe, cWih, cWhh, cWkv, cWq, cWo, cW1, cW2, cPos,
               bias_he, bias_gi, bias_gh, bias_kv, cbq, cbo, cb1, cb2, cbiah, cboah, cln };
  k0_pack<<<1199, 256, 0, stream>>>(pp);
  k1_graph<<<Bb, 256, 0, stream>>>(seqs, alias_g, items_g, rin_g, rout_g, adj_g, adjT_g);
  k2_gather<<<BL*128/256, 256, 0, stream>>>(item_emb, flag, items_g, hidden);
  gemm<128, 256><<<BL/64, 256, 0, stream>>>(hidden, cWhe, bias_he, he);
  k3_agg<<<Bb, 256, 0, stream>>>(he, adj_g, adjT_g, rin_g, rout_g, cbiah, cboah, hio);
  gemm<256, 384><<<BL/64, 256, 0, stream>>>(hio, cWih, bias_gi, gi);
  gemm<128, 384><<<BL/64, 256, 0, stream>>>(hidden, cWhh, bias_gh, gh);
  k4_gru<<<BL*128/256, 256, 0, stream>>>(gi, gh, hidden);
  k5_x<<<BL*128/256, 256, 0, stream>>>(hidden, alias_g, seqs, lens, cPos, x, ht_g);
  gemm<128, 256><<<BL/64, 256, 0, stream>>>(x, cWkv, bias_kv, kv);
  FinalP fp = { x, kv, ht_g, cWq, cWo, cW1, cW2, cbq, cbo, cb1, cb2, cln, lens, flag, d_out };
  k7_final<<<Bb, 256, 0, stream>>>(fp);
}

// Round 3
// 381.913 us; speedup vs baseline: 1.5555x; 1.5555x over previous
//
#include <hip/hip_runtime.h>
#include <hip/hip_bf16.h>

#define Bb 256
#define Ll 200
#define Dd 128
#define BL (Bb*Ll)

typedef __hip_bfloat16 bf16;
typedef __attribute__((ext_vector_type(8))) short short8;
typedef __attribute__((ext_vector_type(4))) unsigned short ushort4v;
typedef __attribute__((ext_vector_type(4))) float floatx4;

__device__ __forceinline__ float b2f(bf16 v) { return __bfloat162float(v); }
__device__ __forceinline__ bf16  f2b(float v) { return __float2bfloat16(v); }
__device__ __forceinline__ float us2f(unsigned short u) { return __uint_as_float(((unsigned)u) << 16); }
__device__ __forceinline__ unsigned short f2us(float v) { bf16 t = f2b(v); return *(unsigned short*)&t; }
__device__ __forceinline__ float ldf(const void* p, int i, int f32) {
  return f32 ? ((const float*)p)[i] : b2f(((const bf16*)p)[i]);
}

// ---------------------------------------------------------------- K-1: dtype detect (1 wave)
__global__ void k_detect(const unsigned short* __restrict__ w, int* __restrict__ flag) {
  int lane = threadIdx.x;
  unsigned short u = w[lane];
  int e = (u >> 7) & 0xFF;
  unsigned long long bad = __ballot(e >= 0x7F);
  if (lane == 0) *flag = (bad != 0ull) ? 1 : 0;   // 1 = float32, 0 = bf16
}

// ---------------------------------------------------------------- K0: canonicalize weights/biases
struct PackP {
  const void *W_ei,*W_eo,*w_ih,*w_hh,*Wk,*Wv,*Wqp,*Wop,*W1p,*W2p,*pos;
  const void *b_ei,*b_eo,*b_ih,*b_hh,*bk,*bv,*bqp,*bop,*b1p,*b2p,*biah,*boah;
  const void *ln1g,*ln1b,*ln2g,*ln2b,*lnfg,*lnfb;
  const int* flag;
  bf16 *cWhe,*cWih,*cWhh,*cWkv,*cWq,*cWo,*cW1,*cW2,*cPos;
  float *bias_he,*bias_gi,*bias_gh,*bias_kv,*cbq,*cbo,*cb1,*cb2,*cbiah,*cboah,*cln;
};
__global__ __launch_bounds__(256) void k0_pack(PackP p) {
  int idx = blockIdx.x * 256 + threadIdx.x;       // < 306944
  int f32 = *p.flag;
  if (idx < 131072) {
    if (idx < 32768) {
      int r = idx >> 7, c = idx & 127;
      p.cWhe[idx] = f2b(r < 128 ? ldf(p.W_ei, r*128+c, f32) : ldf(p.W_eo, (r-128)*128+c, f32));
    } else p.cWih[idx-32768] = f2b(ldf(p.w_ih, idx-32768, f32));
  } else if (idx < 278528) {
    if (idx < 180224)      p.cWhh[idx-131072] = f2b(ldf(p.w_hh, idx-131072, f32));
    else if (idx < 212992) {
      int i = idx - 180224; int r = i >> 7, c = i & 127;
      p.cWkv[i] = f2b(r < 128 ? ldf(p.Wk, r*128+c, f32) : ldf(p.Wv, (r-128)*128+c, f32));
    }
    else if (idx < 229376) p.cWq[idx-212992] = f2b(ldf(p.Wqp, idx-212992, f32));
    else if (idx < 245760) p.cWo[idx-229376] = f2b(ldf(p.Wop, idx-229376, f32));
    else if (idx < 262144) p.cW1[idx-245760] = f2b(ldf(p.W1p, idx-245760, f32));
    else                   p.cW2[idx-262144] = f2b(ldf(p.W2p, idx-262144, f32));
  } else if (idx < 304128) {
    p.cPos[idx-278528] = f2b(ldf(p.pos, idx-278528, f32));
  } else {
    int j = idx - 304128;                          // < 2816
    if      (j < 256)  p.bias_he[j]     = (j<128) ? ldf(p.b_ei,j,f32) : ldf(p.b_eo,j-128,f32);
    else if (j < 640)  p.bias_gi[j-256] = ldf(p.b_ih, j-256, f32);
    else if (j < 1024) p.bias_gh[j-640] = ldf(p.b_hh, j-640, f32);
    else if (j < 1280) { int c=j-1024; p.bias_kv[c] = (c<128)? ldf(p.bk,c,f32): ldf(p.bv,c-128,f32); }
    else if (j < 1408) p.cbq[j-1280]   = ldf(p.bqp, j-1280, f32);
    else if (j < 1536) p.cbo[j-1408]   = ldf(p.bop, j-1408, f32);
    else if (j < 1664) p.cb1[j-1536]   = ldf(p.b1p, j-1536, f32);
    else if (j < 1792) p.cb2[j-1664]   = ldf(p.b2p, j-1664, f32);
    else if (j < 1920) p.cbiah[j-1792] = ldf(p.biah, j-1792, f32);
    else if (j < 2048) p.cboah[j-1920] = ldf(p.boah, j-1920, f32);
    else {
      int i = j - 2048, g = i >> 7, c2 = i & 127;
      const void* s6 = g==0?p.ln1g: g==1?p.ln1b: g==2?p.ln2g: g==3?p.ln2b: g==4?p.lnfg: p.lnfb;
      p.cln[i] = ldf(s6, c2, f32);
    }
  }
}

// ---------------------------------------------------------------- K1: graph build (one block per batch row)
__global__ __launch_bounds__(256) void k1_graph(const int* __restrict__ seqs,
    int* __restrict__ alias_g, int* __restrict__ items_g,
    float* __restrict__ rin_g, float* __restrict__ rout_g,
    unsigned* __restrict__ adj_g, unsigned* __restrict__ adjT_g)
{
  __shared__ int s[Ll], al[Ll], its[Ll];
  __shared__ unsigned char isf[Ll];
  __shared__ unsigned adjL[Ll*8], adjTL[Ll*8];
  int b = blockIdx.x, t = threadIdx.x;
  if (t < Ll) s[t] = seqs[b*Ll + t];
  for (int i = t; i < Ll*8; i += 256) { adjL[i] = 0u; adjTL[i] = 0u; }
  __syncthreads();
  if (t < Ll) {
    int v = s[t]; bool f = true;
    for (int j = 0; j < t; j++) if (s[j] == v) { f = false; break; }
    isf[t] = f ? 1 : 0; its[t] = 0;
  }
  __syncthreads();
  if (t < Ll) {
    int v = s[t], r = 0;
    for (int j = 0; j < Ll; j++) r += (isf[j] && s[j] < v);
    al[t] = r;
  }
  __syncthreads();
  if (t < Ll && isf[t]) its[al[t]] = s[t];
  if (t < Ll-1 && s[t+1] > 0) {
    int u = al[t], v = al[t+1];
    atomicOr(&adjL [u*8 + (v >> 5)], 1u << (v & 31));
    atomicOr(&adjTL[v*8 + (u >> 5)], 1u << (u & 31));
  }
  __syncthreads();
  if (t < Ll) {
    int od = 0, id = 0;
    for (int wd = 0; wd < 7; wd++) { od += __popc(adjL[t*8+wd]); id += __popc(adjTL[t*8+wd]); }
    rout_g [b*Ll + t] = 1.0f / (float)max(od, 1);
    rin_g  [b*Ll + t] = 1.0f / (float)max(id, 1);
    alias_g[b*Ll + t] = al[t];
    items_g[b*Ll + t] = its[t];
  }
  for (int i = t; i < Ll*8; i += 256) { adj_g[b*Ll*8 + i] = adjL[i]; adjT_g[b*Ll*8 + i] = adjTL[i]; }
}

// ---------------------------------------------------------------- K2: gather item embeddings (vectorized)
__global__ __launch_bounds__(256) void k2_gather(const void* __restrict__ emb, const int* __restrict__ flag,
    const int* __restrict__ items_g, bf16* __restrict__ hidden)
{
  int idx = blockIdx.x * 256 + threadIdx.x;       // < BL*16
  int f32 = *flag;
  int n = idx >> 4, jv = idx & 15;
  int it = items_g[n];
  short8 o;
  if (f32) {
    const float* e = (const float*)emb + (size_t)it * 128 + jv * 8;
#pragma unroll
    for (int j = 0; j < 8; j++) o[j] = (short)f2us(e[j]);
  } else {
    o = ((const short8*)((const bf16*)emb + (size_t)it * 128))[jv];
  }
  ((short8*)hidden)[idx] = o;
}

// ---------------------------------------------------------------- MFMA GEMM: out[m,n] = sum_k A[m,k]*W[n,k] + bias[n]
// grid = BL/128 blocks; each wave: 32 rows (2 m-tiles), W fragment reused for 2 MFMAs.
template<int K, int N>
__global__ __launch_bounds__(256) void gemm(const bf16* __restrict__ A, const bf16* __restrict__ W,
                                            const float* __restrict__ bias, bf16* __restrict__ out)
{
  int wave = threadIdx.x >> 6, lane = threadIdx.x & 63;
  int m0 = blockIdx.x * 128 + wave * 32;
  int q = lane >> 4, mr = lane & 15;
  short8 afr[2][K/32];
#pragma unroll
  for (int m2 = 0; m2 < 2; m2++) {
    const short* Ap = (const short*)A + (size_t)(m0 + m2*16 + mr) * K + q * 8;
#pragma unroll
    for (int kk = 0; kk < K/32; kk++) afr[m2][kk] = *(const short8*)(Ap + kk*32);
  }
  for (int nt = 0; nt < N/16; nt++) {
    int n = nt*16 + mr;
    const short* Wp = (const short*)W + (size_t)n * K + q * 8;
    floatx4 acc0 = {0.f,0.f,0.f,0.f}, acc1 = {0.f,0.f,0.f,0.f};
#pragma unroll
    for (int kk = 0; kk < K/32; kk++) {
      short8 bfr = *(const short8*)(Wp + kk*32);
      acc0 = __builtin_amdgcn_mfma_f32_16x16x32_bf16(afr[0][kk], bfr, acc0, 0, 0, 0);
      acc1 = __builtin_amdgcn_mfma_f32_16x16x32_bf16(afr[1][kk], bfr, acc1, 0, 0, 0);
    }
    float bs = bias[n];
#pragma unroll
    for (int i = 0; i < 4; i++) {     // D: col=lane&15, row=quad*4+i
      out[(size_t)(m0 + q*4 + i) * N + n]      = f2b(acc0[i] + bs);
      out[(size_t)(m0 + 16 + q*4 + i) * N + n] = f2b(acc1[i] + bs);
    }
  }
}

// ---------------------------------------------------------------- K3: sparse graph aggregation (one wave per node)
// grid = Bb*25; wave handles nodes chunk*8+wave and +4. Lanes 0-31: in-channels (0..127),
// lanes 32-63: out-channels (128..255); 4 channels/lane via ushort4.
__global__ __launch_bounds__(256) void k3_agg(const bf16* __restrict__ he,
    const unsigned* __restrict__ adj_g, const unsigned* __restrict__ adjT_g,
    const float* __restrict__ rin_g, const float* __restrict__ rout_g,
    const float* __restrict__ cbiah, const float* __restrict__ cboah, bf16* __restrict__ hio)
{
  int b = blockIdx.x / 25, chunk = blockIdx.x % 25;
  int wave = threadIdx.x >> 6, lane = threadIdx.x & 63;
  bool isIn = lane < 32;
  int c = isIn ? 4*lane : 128 + 4*(lane-32);
  const bf16* heb = he + (size_t)b * Ll * 256;
  bf16* hiob = hio + (size_t)b * Ll * 256;
  float bias0 = isIn ? cbiah[c]   : cboah[c-128];
  float bias1 = isIn ? cbiah[c+1] : cboah[c-127];
  float bias2 = isIn ? cbiah[c+2] : cboah[c-126];
  float bias3 = isIn ? cbiah[c+3] : cboah[c-125];
#pragma unroll
  for (int s = 0; s < 2; s++) {
    int i = chunk*8 + wave + 4*s;
    const unsigned* mrow = (isIn ? adjT_g : adj_g) + ((size_t)b*Ll + i) * 8;
    float a0=0.f, a1=0.f, a2=0.f, a3=0.f;
    for (int wd = 0; wd < 7; wd++) {
      unsigned bits = mrow[wd];
      while (bits) {
        int j = (wd << 5) + __builtin_ctz(bits); bits &= bits - 1;
        ushort4v h4 = *(const ushort4v*)(heb + (size_t)j*256 + c);
        a0 += us2f(h4.x); a1 += us2f(h4.y); a2 += us2f(h4.z); a3 += us2f(h4.w);
      }
    }
    float r = isIn ? rin_g[b*Ll + i] : rout_g[b*Ll + i];
    ushort4v o;
    o.x = f2us(bias0 + r*a0); o.y = f2us(bias1 + r*a1);
    o.z = f2us(bias2 + r*a2); o.w = f2us(bias3 + r*a3);
    *(ushort4v*)(hiob + (size_t)i*256 + c) = o;
  }
}

// ---------------------------------------------------------------- K4: GRU cell elementwise (vectorized)
__global__ __launch_bounds__(256) void k4_gru(const bf16* __restrict__ gi, const bf16* __restrict__ gh,
                                              bf16* __restrict__ hidden)
{
  int idx = blockIdx.x * 256 + threadIdx.x;       // < BL*16
  int n = idx >> 4, jv = idx & 15;
  const short8* gin = (const short8*)(gi + (size_t)n * 384);
  const short8* ghn = (const short8*)(gh + (size_t)n * 384);
  short8 vir = gin[jv], vii = gin[16+jv], vnn = gin[32+jv];
  short8 whr = ghn[jv], whi = ghn[16+jv], whn = ghn[32+jv];
  short8 hv  = ((const short8*)hidden)[idx];
  short8 o;
#pragma unroll
  for (int e = 0; e < 8; e++) {
    float ir = us2f((unsigned short)vir[e]), ii = us2f((unsigned short)vii[e]), inn = us2f((unsigned short)vnn[e]);
    float hr = us2f((unsigned short)whr[e]), hi = us2f((unsigned short)whi[e]), hn = us2f((unsigned short)whn[e]);
    float r  = 1.f / (1.f + __expf(-(ir + hr)));
    float z  = 1.f / (1.f + __expf(-(ii + hi)));
    float arg = inn + r * hn;
    float ex = __expf(-2.f * arg);
    float ng = (1.f - ex) / (1.f + ex);
    float h  = us2f((unsigned short)hv[e]);
    o[e] = (short)f2us(ng + z * (h - ng));
  }
  ((short8*)hidden)[idx] = o;
}

// ---------------------------------------------------------------- K5: seq gather + pos emb + mask; save ht
__global__ __launch_bounds__(256) void k5_x(const bf16* __restrict__ hidden, const int* __restrict__ alias_g,
    const int* __restrict__ seqs, const int* __restrict__ lens,
    const bf16* __restrict__ cPos, bf16* __restrict__ x, float* __restrict__ ht)
{
  int idx = blockIdx.x * 256 + threadIdx.x;       // < BL*16
  int jv = idx & 15; int bt = idx >> 4; int tpos = bt % Ll; int b = bt / Ll;
  int a = alias_g[bt];
  short8 hv = ((const short8*)(hidden + ((size_t)b*Ll + a) * Dd))[jv];
  short8 pv = ((const short8*)(cPos + tpos * Dd))[jv];
  bool valid = seqs[bt] > 0;
  bool isLast = (tpos == lens[b] - 1);
  short8 o;
#pragma unroll
  for (int e = 0; e < 8; e++) {
    float sh = us2f((unsigned short)hv[e]);
    float val = valid ? sh + us2f((unsigned short)pv[e]) : 0.f;
    o[e] = (short)f2us(val);
    if (isLast) ht[b*Dd + jv*8 + e] = sh;
  }
  ((short8*)x)[idx] = o;
}

// ---------------------------------------------------------------- K7: per-batch tail
struct FinalP {
  const bf16 *x, *kv; const float* ht;
  const bf16 *cWq, *cWo, *cW1, *cW2;
  const float *cbq, *cbo, *cb1, *cb2, *cln;
  const int* lens; const int* flag;
  void* out;
};
__device__ float block_sum(float v, float* red) {
  int t = threadIdx.x;
  red[t] = v; __syncthreads();
  for (int s = 128; s > 0; s >>= 1) { if (t < s) red[t] += red[t+s]; __syncthreads(); }
  float r = red[0]; __syncthreads(); return r;
}
__device__ float block_max(float v, float* red) {
  int t = threadIdx.x;
  red[t] = v; __syncthreads();
  for (int s = 128; s > 0; s >>= 1) { if (t < s) red[t] = fmaxf(red[t], red[t+s]); __syncthreads(); }
  float r = red[0]; __syncthreads(); return r;
}
__device__ __forceinline__ float dot128(const bf16* __restrict__ wrow, const float* __restrict__ vin) {
  const short8* wr = (const short8*)wrow;
  float acc = 0.f;
#pragma unroll
  for (int kk = 0; kk < 16; kk++) {
    short8 w8 = wr[kk];
#pragma unroll
    for (int j = 0; j < 8; j++) acc += vin[kk*8 + j] * us2f((unsigned short)w8[j]);
  }
  return acc;
}
__global__ __launch_bounds__(256) void k7_final(FinalP p)
{
  __shared__ float red[256];
  __shared__ float pb[256];
  __shared__ float av4[256];
  __shared__ float qin[128], qv[128], aout[128], hh[128], f1[128];
  int b = blockIdx.x, t = threadIdx.x, c = t;
  int li = p.lens[b] - 1;
  int f32 = *p.flag;
  // LN1 on x[b,li]
  float xv = (c < 128) ? b2f(p.x[((size_t)b*Ll + li) * Dd + c]) : 0.f;
  float mu = block_sum((c < 128) ? xv : 0.f, red) * (1.f/128.f);
  float d  = (c < 128) ? xv - mu : 0.f;
  float var = block_sum(d*d, red) * (1.f/128.f);
  float rs = rsqrtf(var + 1e-5f);
  if (c < 128) qin[c] = d * rs * p.cln[c] + p.cln[128+c];
  __syncthreads();
  if (c < 128) qv[c] = p.cbq[c] + dot128(p.cWq + c*128, qin);
  __syncthreads();
  const bf16* kvb = p.kv + (size_t)b * Ll * 256;
  for (int h = 0; h < 2; h++) {
    float sc = -3.0e38f;
    if (t <= li) {
      const short8* kr = (const short8*)(kvb + (size_t)t*256 + h*64);
      float s_ = 0.f;
#pragma unroll
      for (int kk = 0; kk < 8; kk++) {
        short8 k8 = kr[kk];
#pragma unroll
        for (int j = 0; j < 8; j++) s_ += qv[h*64 + kk*8 + j] * us2f((unsigned short)k8[j]);
      }
      sc = s_ * 0.125f;
    }
    float m = block_max(sc, red);
    float e = (t <= li) ? __expf(sc - m) : 0.f;
    pb[t] = e;
    float l = block_sum(e, red);
    // attention * V, 4-way split over keys
    int ch = t & 63, part = t >> 6;
    float accv = 0.f;
    for (int j = part; j <= li; j += 4)
      accv += pb[j] * b2f(kvb[(size_t)j*256 + 128 + h*64 + ch]);
    av4[part*64 + ch] = accv;
    __syncthreads();
    if (t < 64) aout[h*64 + t] = (av4[t] + av4[64+t] + av4[128+t] + av4[192+t]) / l;
    __syncthreads();
  }
  // mo + residual
  float x2v = 0.f;
  if (c < 128) x2v = qin[c] + p.cbo[c] + dot128(p.cWo + c*128, aout);
  // LN2
  mu = block_sum((c < 128) ? x2v : 0.f, red) * (1.f/128.f);
  d  = (c < 128) ? x2v - mu : 0.f;
  var = block_sum(d*d, red) * (1.f/128.f);
  rs = rsqrtf(var + 1e-5f);
  if (c < 128) hh[c] = d * rs * p.cln[256+c] + p.cln[384+c];
  __syncthreads();
  if (c < 128) f1[c] = fmaxf(p.cb1[c] + dot128(p.cW1 + c*128, hh), 0.f);
  __syncthreads();
  float x3v = 0.f;
  if (c < 128) x3v = hh[c] + p.cb2[c] + dot128(p.cW2 + c*128, f1);
  // LNf + mix with ht
  mu = block_sum((c < 128) ? x3v : 0.f, red) * (1.f/128.f);
  d  = (c < 128) ? x3v - mu : 0.f;
  var = block_sum(d*d, red) * (1.f/128.f);
  rs = rsqrtf(var + 1e-5f);
  if (c < 128) {
    float lf = d * rs * p.cln[512+c] + p.cln[640+c];
    float outv = 0.6f * lf + 0.4f * p.ht[b*Dd + c];
    if (f32) ((float*)p.out)[b*Dd + c] = outv;
    else     ((bf16*)p.out)[b*Dd + c]  = f2b(outv);
  }
}

// ---------------------------------------------------------------- host
extern "C" void kernel_launch(void* const* d_in, const int* in_sizes, int n_in,
                              void* d_out, int out_size, void* d_ws, size_t ws_size,
                              hipStream_t stream)
{
  (void)in_sizes; (void)n_in; (void)out_size; (void)ws_size;
  const void* item_emb = d_in[0];
  const int* seqs = (const int*)d_in[30];
  const int* lens = (const int*)d_in[31];

  char* wsp = (char*)d_ws;
  size_t o = 0;
  auto alloc = [&](size_t sz) { void* p = wsp + o; o += (sz + 255) & ~(size_t)255; return p; };
  int*      flag    = (int*)alloc(4);
  int*      alias_g = (int*)alloc((size_t)BL*4);
  int*      items_g = (int*)alloc((size_t)BL*4);
  float*    rin_g   = (float*)alloc((size_t)BL*4);
  float*    rout_g  = (float*)alloc((size_t)BL*4);
  unsigned* adj_g   = (unsigned*)alloc((size_t)BL*8*4);
  unsigned* adjT_g  = (unsigned*)alloc((size_t)BL*8*4);
  float*    ht_g    = (float*)alloc((size_t)Bb*Dd*4);
  bf16*     cWhe    = (bf16*)alloc(32768*2);
  bf16*     cWih    = (bf16*)alloc(98304*2);
  bf16*     cWhh    = (bf16*)alloc(49152*2);
  bf16*     cWkv    = (bf16*)alloc(32768*2);
  bf16*     cWq     = (bf16*)alloc(16384*2);
  bf16*     cWo     = (bf16*)alloc(16384*2);
  bf16*     cW1     = (bf16*)alloc(16384*2);
  bf16*     cW2     = (bf16*)alloc(16384*2);
  bf16*     cPos    = (bf16*)alloc(25600*2);
  float*    bias_he = (float*)alloc(256*4);
  float*    bias_gi = (float*)alloc(384*4);
  float*    bias_gh = (float*)alloc(384*4);
  float*    bias_kv = (float*)alloc(256*4);
  float*    cbq     = (float*)alloc(128*4);
  float*    cbo     = (float*)alloc(128*4);
  float*    cb1     = (float*)alloc(128*4);
  float*    cb2     = (float*)alloc(128*4);
  float*    cbiah   = (float*)alloc(128*4);
  float*    cboah   = (float*)alloc(128*4);
  float*    cln     = (float*)alloc(768*4);
  bf16*     hidden  = (bf16*)alloc((size_t)BL*128*2);
  bf16*     he      = (bf16*)alloc((size_t)BL*256*2);
  bf16*     hio     = (bf16*)alloc((size_t)BL*256*2);
  bf16*     gi      = (bf16*)alloc((size_t)BL*384*2);
  bf16*     gh      = (bf16*)alloc((size_t)BL*384*2);
  bf16*     x  = he;    // reuse: he dead after k3_agg
  bf16*     kv = hio;   // reuse: hio dead after gi GEMM

  k_detect<<<1, 64, 0, stream>>>((const unsigned short*)d_in[2], flag);
  PackP pp = { d_in[2], d_in[4], d_in[8], d_in[10], d_in[16], d_in[18], d_in[14], d_in[20],
               d_in[24], d_in[26], d_in[1],
               d_in[3], d_in[5], d_in[9], d_in[11], d_in[17], d_in[19], d_in[15], d_in[21],
               d_in[25], d_in[27], d_in[6], d_in[7],
               d_in[12], d_in[13], d_in[22], d_in[23], d_in[28], d_in[29],
               flag,
               cWhe, cWih, cWhh, cWkv, cWq, cWo, cW1, cW2, cPos,
               bias_he, bias_gi, bias_gh, bias_kv, cbq, cbo, cb1, cb2, cbiah, cboah, cln };
  k0_pack<<<1199, 256, 0, stream>>>(pp);
  k1_graph<<<Bb, 256, 0, stream>>>(seqs, alias_g, items_g, rin_g, rout_g, adj_g, adjT_g);
  k2_gather<<<BL*16/256, 256, 0, stream>>>(item_emb, flag, items_g, hidden);
  gemm<128, 256><<<BL/128, 256, 0, stream>>>(hidden, cWhe, bias_he, he);
  k3_agg<<<Bb*25, 256, 0, stream>>>(he, adj_g, adjT_g, rin_g, rout_g, cbiah, cboah, hio);
  gemm<256, 384><<<BL/128, 256, 0, stream>>>(hio, cWih, bias_gi, gi);
  gemm<128, 384><<<BL/128, 256, 0, stream>>>(hidden, cWhh, bias_gh, gh);
  k4_gru<<<BL*16/256, 256, 0, stream>>>(gi, gh, hidden);
  k5_x<<<BL*16/256, 256, 0, stream>>>(hidden, alias_g, seqs, lens, cPos, x, ht_g);
  gemm<128, 256><<<BL/128, 256, 0, stream>>>(x, cWkv, bias_kv, kv);
  FinalP fp = { x, kv, ht_g, cWq, cWo, cW1, cW2, cbq, cbo, cb1, cb2, cln, lens, flag, d_out };
  k7_final<<<Bb, 256, 0, stream>>>(fp);
}